// Round 2
// baseline (2513.008 us; speedup 1.0000x reference)
//
#include <hip/hip_runtime.h>
#include <hip/hip_bf16.h>

typedef __bf16 bf16;
typedef __attribute__((ext_vector_type(8))) __bf16 bf16x8;
typedef __attribute__((ext_vector_type(4))) float f32x4;

#define MFMA16(a, b, c) __builtin_amdgcn_mfma_f32_16x16x32_bf16((a), (b), (c), 0, 0, 0)

__device__ __forceinline__ void async16(const bf16* g, bf16* l) {
    __builtin_amdgcn_global_load_lds((__attribute__((address_space(1))) void*)(g),
                                     (__attribute__((address_space(3))) void*)(l), 16, 0, 0);
}

// Bijective XCD-chunked swizzle (m204): blocks with consecutive remapped
// linear ids land on the SAME XCD, so blocks sharing an A-panel (same by)
// or the same (b,h) KV get private-L2 reuse instead of L3/HBM re-fetch.
__device__ __forceinline__ void xcd_swizzle(int& bx, int& by, int& bz) {
    const int gx = gridDim.x, gy = gridDim.y;
    const int nwg = gx * gy * gridDim.z;
    const int lin = blockIdx.x + gx * (blockIdx.y + gy * blockIdx.z);
    const int xcd = lin & 7, seq = lin >> 3;
    const int q = nwg >> 3, r = nwg & 7;
    const int nl = (xcd < r ? xcd * (q + 1) : r * (q + 1) + (xcd - r) * q) + seq;
    bx = nl % gx;
    const int t = nl / gx;
    by = t % gy;
    bz = t / gy;
}

// ---------------------------------------------------------------------------
// GEMM: C[M,N] = A[M,K-slice] @ WT[N,K-slice]^T (+ bias for MODE 0/2).
// MODE 0: bf16 out (+bias); MODE 1: f32 partial out, NO bias (reduced in ln);
// MODE 2: gelu(exact)+bias, bf16 out.
// BM in {64,128}, BN=128, BK=32; 256 thr = 4 waves 2x2.
// 2-phase double-buffered pipeline, one __syncthreads per K-iter.
// Split-K (<=2) via blockIdx.z.  XCD-chunked swizzle for A-panel L2 reuse.
// ---------------------------------------------------------------------------
template <int MODE, int BM>
__global__ __launch_bounds__(256) void gemm_kernel(
    const bf16* __restrict__ A, const bf16* __restrict__ WT,
    const float* __restrict__ b0, const float* __restrict__ b1, const float* __restrict__ b2,
    int s1, int s2,
    void* __restrict__ o0, void* __restrict__ o1,
    int N, int K, int Kpart)
{
    constexpr int MT = BM / 32;              // 16-row frags per wave (rows)
    __shared__ __align__(16) bf16 sA[2][BM * 32];
    __shared__ __align__(16) bf16 sB[2][128 * 32];

    const int tid  = threadIdx.x;
    const int lane = tid & 63;
    const int wave = tid >> 6;
    const int quad = lane >> 4;
    const int l15  = lane & 15;
    const int wm   = (wave >> 1) * (BM / 2);
    const int wn   = (wave & 1) * 64;

    int bxs, bys, bzs;
    xcd_swizzle(bxs, bys, bzs);
    const int bm = bys * BM;
    const int bn = bxs * 128;
    const int kbase = bzs * Kpart;

    f32x4 acc[MT][4];
#pragma unroll
    for (int i = 0; i < MT; i++)
#pragma unroll
        for (int j = 0; j < 4; j++)
#pragma unroll
            for (int r = 0; r < 4; r++) acc[i][j][r] = 0.0f;

    const int idx1 = tid + 256;
    const int ra0 = tid  >> 2, ca0 = (tid  & 3) * 8;
    const int rb1 = idx1 >> 2, cb1 = (idx1 & 3) * 8;

    const bf16* Arow0 = A  + (size_t)(bm + ra0) * K + kbase + ca0;
    const bf16* Arow1 = A  + (size_t)(bm + rb1) * K + kbase + cb1;   // BM==128 only
    const bf16* Brow0 = WT + (size_t)(bn + ra0) * K + kbase + ca0;
    const bf16* Brow1 = WT + (size_t)(bn + rb1) * K + kbase + cb1;

    const int nk = Kpart >> 5;

    // prologue: stage tile 0 into buffer 0
    async16(Arow0, sA[0] + tid * 8);
    if (BM == 128) async16(Arow1, sA[0] + idx1 * 8);
    async16(Brow0, sB[0] + tid * 8);
    async16(Brow1, sB[0] + idx1 * 8);
    __syncthreads();   // vmcnt(0) drained -> tile 0 visible

    int cur = 0;
    for (int kt = 0; kt < nk; kt++) {
        if (kt + 1 < nk) {
            const int ko = (kt + 1) * 32;
            async16(Arow0 + ko, sA[cur ^ 1] + tid * 8);
            if (BM == 128) async16(Arow1 + ko, sA[cur ^ 1] + idx1 * 8);
            async16(Brow0 + ko, sB[cur ^ 1] + tid * 8);
            async16(Brow1 + ko, sB[cur ^ 1] + idx1 * 8);
        }
        bf16x8 af[MT], bfr[4];
#pragma unroll
        for (int i = 0; i < MT; i++)
            af[i] = *(const bf16x8*)(sA[cur] + (wm + i * 16 + l15) * 32 + quad * 8);
#pragma unroll
        for (int i = 0; i < 4; i++)
            bfr[i] = *(const bf16x8*)(sB[cur] + (wn + i * 16 + l15) * 32 + quad * 8);
#pragma unroll
        for (int mt = 0; mt < MT; mt++)
#pragma unroll
            for (int nt = 0; nt < 4; nt++)
                acc[mt][nt] = MFMA16(af[mt], bfr[nt], acc[mt][nt]);
        // one barrier: (a) drains vmcnt(0) -> tile t+1 landed;
        // (b) all waves done reading buf[cur] -> safe to overwrite next iter.
        __syncthreads();
        cur ^= 1;
    }

    void* outp = (bzs == 0) ? o0 : o1;

    // epilogue: C/D layout col = lane&15, row = quad*4 + r
#pragma unroll
    for (int nt = 0; nt < 4; nt++) {
        const int col = bn + wn + nt * 16 + l15;
        float bias = 0.0f;
        if (MODE != 1)
            bias = (col < s1) ? b0[col] : (col < s2) ? b1[col - s1] : b2[col - s2];
#pragma unroll
        for (int mt = 0; mt < MT; mt++) {
#pragma unroll
            for (int r = 0; r < 4; r++) {
                const int row = bm + wm + mt * 16 + quad * 4 + r;
                float v = acc[mt][nt][r] + bias;
                if (MODE == 2) v = 0.5f * v * (1.0f + erff(v * 0.70710678118654752f));
                if (MODE == 1) ((float*)outp)[(size_t)row * N + col] = v;
                else           ((bf16*)outp)[(size_t)row * N + col] = (bf16)v;
            }
        }
    }
}

// ---------------------------------------------------------------------------
// V-transpose: qkv V-part [key][dim] -> vT[bh][dim][key], coalesced both ways.
// ---------------------------------------------------------------------------
__global__ __launch_bounds__(256) void vtrans_kernel(
    const bf16* __restrict__ qkv, bf16* __restrict__ vT)
{
    const int bh = blockIdx.y;           // b*12 + h
    const int b = bh / 12, h = bh - b * 12;
    const int k0 = blockIdx.x * 128;
    __shared__ __align__(16) bf16 tile[128 * 72];
    const int tid = threadIdx.x;
    const bf16* src = qkv + (size_t)(b * 512 + k0) * 2304 + 1536 + h * 64;
#pragma unroll
    for (int i = 0; i < 4; i++) {
        const int idx = i * 256 + tid;
        const int r = idx >> 3, c = (idx & 7) * 8;      // key r, dim c
        *(uint4*)(tile + r * 72 + c) = *(const uint4*)(src + (size_t)r * 2304 + c);
    }
    __syncthreads();
    bf16* dst = vT + (size_t)bh * 64 * 512 + k0;
#pragma unroll
    for (int i = 0; i < 4; i++) {
        const int idx = i * 256 + tid;
        const int d = idx & 63, kg = idx >> 6;          // dim d, key-group kg
        alignas(16) bf16 tmp[8];
#pragma unroll
        for (int e = 0; e < 8; e++) tmp[e] = tile[(kg * 8 + e) * 72 + d];
        *(uint4*)(dst + (size_t)d * 512 + kg * 8) = *(uint4*)tmp;
    }
}

// ---------------------------------------------------------------------------
// Attention: one block = (b, h, 32-row Q tile), 256 threads = 4 waves.
// XCD-swizzled so the 16 Q-tile blocks of one (b,h) share an XCD's L2 (K/V).
// ---------------------------------------------------------------------------
__global__ __launch_bounds__(256) void attn_kernel(
    const bf16* __restrict__ qkv, const bf16* __restrict__ vT,
    const float* __restrict__ mask, bf16* __restrict__ ctx)
{
    int bxs, bys, bzs;
    xcd_swizzle(bxs, bys, bzs);
    const int b = bzs, h = bys, q0 = bxs * 32;
    const int bh = b * 12 + h;
    const int tid = threadIdx.x, lane = tid & 63, wave = tid >> 6;
    const int quad = lane >> 4, l15 = lane & 15;
    const int mt = wave & 1;             // row half (0..1)
    const int whi = wave >> 1;           // col half (0..1)

    __shared__ __align__(16) bf16 sQ[32 * 80];
    __shared__ __align__(16) bf16 sKV[64 * 80];
    __shared__ __align__(16) bf16 sS[32 * 520];
    __shared__ float sAM[512];
    __shared__ float sRedM[32 * 8];
    __shared__ float sRedS[32 * 8];
    __shared__ float sRow[32];

    for (int i = tid; i < 512; i += 256)
        sAM[i] = (1.0f - mask[b * 512 + i]) * -10000.0f;

    const size_t RS = 2304;
    {
        const int r = tid >> 3, c = (tid & 7) * 8;
        *(uint4*)(sQ + r * 80 + c) =
            *(const uint4*)(qkv + (size_t)(b * 512 + q0 + r) * RS + h * 64 + c);
    }

    // ---- phase B: S = Q @ K^T ----
#pragma unroll 1
    for (int kt = 0; kt < 8; kt++) {
        __syncthreads();
        const bf16* Kb = qkv + (size_t)(b * 512 + kt * 64) * RS + 768 + h * 64;
#pragma unroll
        for (int i = 0; i < 2; i++) {
            const int idx = i * 256 + tid;
            const int r = idx >> 3, c = (idx & 7) * 8;
            *(uint4*)(sKV + r * 80 + c) = *(const uint4*)(Kb + (size_t)r * RS + c);
        }
        __syncthreads();
        bf16x8 aQ0 = *(const bf16x8*)(sQ + (mt * 16 + l15) * 80 + quad * 8);
        bf16x8 aQ1 = *(const bf16x8*)(sQ + (mt * 16 + l15) * 80 + 32 + quad * 8);
#pragma unroll
        for (int n = 0; n < 2; n++) {
            const int nt = whi * 2 + n;
            f32x4 accS;
#pragma unroll
            for (int r = 0; r < 4; r++) accS[r] = 0.0f;
            accS = MFMA16(aQ0, *(const bf16x8*)(sKV + (nt * 16 + l15) * 80 + quad * 8), accS);
            accS = MFMA16(aQ1, *(const bf16x8*)(sKV + (nt * 16 + l15) * 80 + 32 + quad * 8), accS);
#pragma unroll
            for (int r = 0; r < 4; r++) {
                const int row = mt * 16 + quad * 4 + r;
                sS[row * 520 + kt * 64 + nt * 16 + l15] = (bf16)accS[r];
            }
        }
    }
    __syncthreads();

    // ---- phase C: softmax ----
    {
        const int r = tid >> 3, p = tid & 7;    // row 0..31, chunk 0..7
        float mx = -1e30f;
#pragma unroll
        for (int t = 0; t < 8; t++) {
            const int v0 = (p + 8 * t) * 8;
            bf16x8 pv = *(const bf16x8*)(sS + r * 520 + v0);
#pragma unroll
            for (int e = 0; e < 8; e++)
                mx = fmaxf(mx, (float)pv[e] * 0.125f + sAM[v0 + e]);
        }
        sRedM[r * 8 + p] = mx;
        __syncthreads();
#pragma unroll
        for (int q = 0; q < 8; q++) mx = fmaxf(mx, sRedM[r * 8 + q]);
        float sum = 0.0f;
#pragma unroll
        for (int t = 0; t < 8; t++) {
            const int v0 = (p + 8 * t) * 8;
            bf16x8 pv = *(const bf16x8*)(sS + r * 520 + v0);
            bf16x8 ev;
#pragma unroll
            for (int e = 0; e < 8; e++) {
                const float x = __expf((float)pv[e] * 0.125f + sAM[v0 + e] - mx);
                sum += x;
                ev[e] = (bf16)x;
            }
            *(bf16x8*)(sS + r * 520 + v0) = ev;
        }
        sRedS[r * 8 + p] = sum;
        __syncthreads();
        if (p == 0) {
            float s = 0.0f;
#pragma unroll
            for (int q = 0; q < 8; q++) s += sRedS[r * 8 + q];
            sRow[r] = s;
        }
    }

    // ---- phase D: O = P @ V ----
    f32x4 accO[2];
#pragma unroll
    for (int i = 0; i < 2; i++)
#pragma unroll
        for (int r = 0; r < 4; r++) accO[i][r] = 0.0f;

#pragma unroll 1
    for (int kt = 0; kt < 8; kt++) {
        __syncthreads();
        const bf16* Vt = vT + (size_t)bh * 64 * 512 + kt * 64;
#pragma unroll
        for (int i = 0; i < 2; i++) {
            const int idx = i * 256 + tid;
            const int r = idx >> 3, c = (idx & 7) * 8;  // dim r, key c
            *(uint4*)(sKV + r * 80 + c) = *(const uint4*)(Vt + (size_t)r * 512 + c);
        }
        __syncthreads();
#pragma unroll
        for (int kk = 0; kk < 2; kk++) {
            bf16x8 aP = *(const bf16x8*)(sS + (mt * 16 + l15) * 520 + kt * 64 + kk * 32 + quad * 8);
#pragma unroll
            for (int n = 0; n < 2; n++) {
                bf16x8 bV = *(const bf16x8*)(sKV + (whi * 32 + n * 16 + l15) * 80 + kk * 32 + quad * 8);
                accO[n] = MFMA16(aP, bV, accO[n]);
            }
        }
    }
#pragma unroll
    for (int n = 0; n < 2; n++) {
#pragma unroll
        for (int r = 0; r < 4; r++) {
            const int row = mt * 16 + quad * 4 + r;
            const float o = accO[n][r] / sRow[row];
            ctx[(size_t)(b * 512 + q0 + row) * 768 + h * 64 + whi * 32 + n * 16 + l15] = (bf16)o;
        }
    }
}

// ---------------------------------------------------------------------------
// Fused split-K reduce + bias + residual-add + LayerNorm.
// One block (256 thr) per row of 768. NP = number of f32 partial inputs.
// ---------------------------------------------------------------------------
template <int NP>
__global__ __launch_bounds__(256) void ln_kernel(
    const float* __restrict__ p0, const float* __restrict__ p1,
    const float* __restrict__ bias, const float* __restrict__ resid,
    const float* __restrict__ g, const float* __restrict__ bb,
    bf16* __restrict__ out_bf, float* __restrict__ out_f32)
{
    const int row = blockIdx.x;
    const int tid = threadIdx.x;
    __shared__ float sS[4], sQ[4];

    float x[3], s = 0.0f, sq = 0.0f;
#pragma unroll
    for (int j = 0; j < 3; j++) {
        const int c = tid + j * 256;
        const size_t idx = (size_t)row * 768 + c;
        float v = p0[idx] + bias[c] + resid[idx];
        if (NP > 1) v += p1[idx];
        x[j] = v; s += v; sq += v * v;
    }
#pragma unroll
    for (int off = 32; off; off >>= 1) { s += __shfl_down(s, off); sq += __shfl_down(sq, off); }
    if ((tid & 63) == 0) { sS[tid >> 6] = s; sQ[tid >> 6] = sq; }
    __syncthreads();
    s  = sS[0] + sS[1] + sS[2] + sS[3];
    sq = sQ[0] + sQ[1] + sQ[2] + sQ[3];
    const float mean = s * (1.0f / 768.0f);
    float var = sq * (1.0f / 768.0f) - mean * mean;
    var = fmaxf(var, 0.0f);
    const float rstd = rsqrtf(var + 1e-12f);
#pragma unroll
    for (int j = 0; j < 3; j++) {
        const int c = tid + j * 256;
        const float v = (x[j] - mean) * rstd * g[c] + bb[c];
        out_bf[(size_t)row * 768 + c] = (bf16)v;
        out_f32[(size_t)row * 768 + c] = v;
    }
}

// ---------------------------------------------------------------------------
// Transpose + quantize all 6 fp32 weight matrices of one layer into bf16 wT.
// ---------------------------------------------------------------------------
__global__ __launch_bounds__(256) void transpose_kernel(
    const float* __restrict__ Wq, const float* __restrict__ Wk, const float* __restrict__ Wv,
    const float* __restrict__ Wao, const float* __restrict__ Wi, const float* __restrict__ Wo,
    bf16* __restrict__ wT)
{
    __shared__ bf16 tile[64 * 68];
    int id = blockIdx.x;
    const float* src; bf16* dst; int Kd, Nd;
    if (id < 576) {
        const int w = id / 144; id -= w * 144;
        Kd = 768; Nd = 768;
        src = (w == 0) ? Wq : (w == 1) ? Wk : (w == 2) ? Wv : Wao;
        dst = wT + (size_t)w * 589824;
    } else if (id < 1152) {
        id -= 576; Kd = 768; Nd = 3072; src = Wi; dst = wT + 2359296;
    } else {
        id -= 1152; Kd = 3072; Nd = 768; src = Wo; dst = wT + 4718592;
    }
    const int tn = Nd >> 6;
    const int tr = id / tn, tc = id - tr * tn;
    const int r0 = tr * 64, c0 = tc * 64;
    const int tid = threadIdx.x;

#pragma unroll
    for (int i = 0; i < 4; i++) {
        const int idx = i * 256 + tid;
        const int r = idx >> 4, c4 = (idx & 15) * 4;
        const float4 f = *(const float4*)(src + (size_t)(r0 + r) * Nd + c0 + c4);
        alignas(8) bf16 q[4] = {(bf16)f.x, (bf16)f.y, (bf16)f.z, (bf16)f.w};
        *(ushort4*)(tile + r * 68 + c4) = *(ushort4*)q;
    }
    __syncthreads();
#pragma unroll
    for (int i = 0; i < 4; i++) {
        const int idx = i * 256 + tid;
        const int n = idx >> 4, kc = (idx & 15) * 4;
        alignas(8) bf16 tmp[4];
#pragma unroll
        for (int e = 0; e < 4; e++) tmp[e] = tile[(kc + e) * 68 + n];
        *(ushort4*)(dst + (size_t)(c0 + n) * Kd + r0 + kc) = *(ushort4*)tmp;
    }
}

__global__ __launch_bounds__(256) void convert_kernel(
    const float* __restrict__ in, bf16* __restrict__ out, int n)
{
    const int i = blockIdx.x * 256 + threadIdx.x;
    if (i < n) out[i] = (bf16)in[i];
}

// ---------------------------------------------------------------------------
extern "C" void kernel_launch(void* const* d_in, const int* in_sizes, int n_in,
                              void* d_out, int out_size, void* d_ws, size_t ws_size,
                              hipStream_t stream)
{
    const float* hidden = (const float*)d_in[0];
    const float* mask   = (const float*)d_in[1];
    const float* Wq  = (const float*)d_in[2];  const float* bq  = (const float*)d_in[3];
    const float* Wk  = (const float*)d_in[4];  const float* bk  = (const float*)d_in[5];
    const float* Wv  = (const float*)d_in[6];  const float* bv  = (const float*)d_in[7];
    const float* Wao = (const float*)d_in[8];  const float* bao = (const float*)d_in[9];
    const float* g1  = (const float*)d_in[10]; const float* be1 = (const float*)d_in[11];
    const float* Wi  = (const float*)d_in[12]; const float* bi  = (const float*)d_in[13];
    const float* Wo  = (const float*)d_in[14]; const float* bo  = (const float*)d_in[15];
    const float* g2  = (const float*)d_in[16]; const float* be2 = (const float*)d_in[17];

    // workspace layout (95,944,704 B):
    //   wT    [0,          14155776)   bf16 weights (per-layer, transposed)
    //   qkv   [14155776,   33030144)   bf16 4096x2304   (dead after attn)
    //   vT    [33030144,   39321600)   bf16             (dead after attn)
    //   ctx   [39321600,   45613056)   bf16 4096x768    (dead after AO gemm)
    //   attnb [45613056,   51904512)   bf16             (dead after FF1)
    //   xb    [51904512,   58195968)   bf16             (dead after QKV)
    //   xf    [58195968,   70778880)   f32  resid1      (dead after ln1)
    //   attnf [70778880,   83361792)   f32  resid2      (dead after ln2)
    //   spare [83361792,   95944704)   f32 partial buffer
    // aliases (lifetime-checked):
    //   ffh = qkv+vT [14155776, 39321600)  bf16 4096x3072 (FF1 out / FF2 in)
    //   pA0 = 14155776            (AO f32 out; qkv dead after attn)
    //   pF0 = 39321600 (ctx+attnb), pF1 = spare   (FF2 split-2 partials)
    char* ws = (char*)d_ws;
    bf16*  wT    = (bf16*)(ws);
    bf16*  qkv   = (bf16*)(ws + 14155776);
    bf16*  vT    = (bf16*)(ws + 33030144);
    bf16*  ctx   = (bf16*)(ws + 39321600);
    bf16*  attnb = (bf16*)(ws + 45613056);
    bf16*  xb    = (bf16*)(ws + 51904512);
    float* xf    = (float*)(ws + 58195968);
    float* attnf = (float*)(ws + 70778880);
    bf16*  ffh   = (bf16*)(ws + 14155776);
    float* pA0   = (float*)(ws + 14155776);
    float* pF0   = (float*)(ws + 39321600);
    float* pF1   = (float*)(ws + 83361792);

    convert_kernel<<<12288, 256, 0, stream>>>(hidden, xb, 3145728);

    for (int l = 0; l < 12; l++) {
        transpose_kernel<<<1728, 256, 0, stream>>>(
            Wq + (size_t)l * 589824, Wk + (size_t)l * 589824, Wv + (size_t)l * 589824,
            Wao + (size_t)l * 589824, Wi + (size_t)l * 2359296, Wo + (size_t)l * 2359296, wT);

        // QKV: M=4096 N=2304 K=768, BM=64 -> 18x64 = 1152 blocks (4.5/CU)
        gemm_kernel<0, 64><<<dim3(18, 64, 1), 256, 0, stream>>>(
            xb, wT, bq + l * 768, bk + l * 768, bv + l * 768, 768, 1536,
            qkv, nullptr, 2304, 768, 768);

        vtrans_kernel<<<dim3(4, 96), 256, 0, stream>>>(qkv, vT);

        attn_kernel<<<dim3(16, 12, 8), 256, 0, stream>>>(qkv, vT, mask, ctx);

        // AO: M=4096 N=768 K=768, BM=64 no split -> 6x64 = 384 blocks, f32 out
        gemm_kernel<1, 64><<<dim3(6, 64, 1), 256, 0, stream>>>(
            ctx, wT + 1769472, nullptr, nullptr, nullptr, 0, 0,
            pA0, nullptr, 768, 768, 768);

        const float* resid1 = (l == 0) ? hidden : xf;
        ln_kernel<1><<<4096, 256, 0, stream>>>(
            pA0, nullptr, bao + l * 768, resid1, g1 + l * 768, be1 + l * 768, attnb, attnf);

        // FF1: M=4096 N=3072 K=768, BM=128 -> 24x32 = 768 blocks
        gemm_kernel<2, 128><<<dim3(24, 32, 1), 256, 0, stream>>>(
            attnb, wT + 2359296, bi + l * 3072, bi + l * 3072, bi + l * 3072, 3072, 3072,
            ffh, nullptr, 3072, 768, 768);

        // FF2: M=4096 N=768 K=3072, BM=64 split-2 -> 6x64x2 = 768 blocks
        gemm_kernel<1, 64><<<dim3(6, 64, 2), 256, 0, stream>>>(
            ffh, wT + 4718592, nullptr, nullptr, nullptr, 0, 0,
            pF0, pF1, 768, 3072, 1536);

        float* f32dst = (l == 11) ? (float*)d_out : xf;
        ln_kernel<2><<<4096, 256, 0, stream>>>(
            pF0, pF1, bo + l * 768, attnf, g2 + l * 768, be2 + l * 768, xb, f32dst);
    }
}

// Round 3
// 2462.323 us; speedup vs baseline: 1.0206x; 1.0206x over previous
//
#include <hip/hip_runtime.h>
#include <hip/hip_bf16.h>

typedef __bf16 bf16;
typedef __attribute__((ext_vector_type(8))) __bf16 bf16x8;
typedef __attribute__((ext_vector_type(4))) float f32x4;

#define MFMA16(a, b, c) __builtin_amdgcn_mfma_f32_16x16x32_bf16((a), (b), (c), 0, 0, 0)

// Counted-vmcnt sync: wait for all but the N newest vmem ops (the in-flight
// prefetch), then barrier. sched_barrier pins code below the barrier.
#define SYNC_VM(N) do { asm volatile("s_waitcnt vmcnt(" #N ")" ::: "memory"); \
    __builtin_amdgcn_s_barrier(); __builtin_amdgcn_sched_barrier(0); } while (0)
// End-of-phase sync: LDS reads/writes retired (WAR guard), no vmcnt drain.
#define SYNC_LGKM() do { asm volatile("s_waitcnt lgkmcnt(0)" ::: "memory"); \
    __builtin_amdgcn_s_barrier(); __builtin_amdgcn_sched_barrier(0); } while (0)

__device__ __forceinline__ void async16(const bf16* g, bf16* l) {
    __builtin_amdgcn_global_load_lds((__attribute__((address_space(1))) void*)(g),
                                     (__attribute__((address_space(3))) void*)(l), 16, 0, 0);
}

// Bijective XCD-chunked swizzle (m204).
__device__ __forceinline__ void xcd_swizzle(int& bx, int& by, int& bz) {
    const int gx = gridDim.x, gy = gridDim.y;
    const int nwg = gx * gy * gridDim.z;
    const int lin = blockIdx.x + gx * (blockIdx.y + gy * blockIdx.z);
    const int xcd = lin & 7, seq = lin >> 3;
    const int q = nwg >> 3, r = nwg & 7;
    const int nl = (xcd < r ? xcd * (q + 1) : r * (q + 1) + (xcd - r) * q) + seq;
    bx = nl % gx;
    const int t = nl / gx;
    by = t % gy;
    bz = t / gy;
}

// ---------------------------------------------------------------------------
// GEMM: C[M,N] = A[M,K-slice] @ WT[N,K-slice]^T (+ bias for MODE 0/2).
// MODE 0: bf16 out (+bias); MODE 1: f32 partial out, NO bias; MODE 2: gelu+bias.
// BM in {64,128}, BN=128, BK=32; 256 thr = 4 waves 2x2.
// Counted-vmcnt double-buffer: stage(t+1) issued, then vmcnt(NL) waits only
// for tile t; prefetch stays in flight across both barriers (T4).
// LDS tiles chunk-XOR swizzled: LDS[r][chunk j] = G[r][chunk j ^ ((r>>1)&3)]
// (source pre-swizzled, linear global_load_lds dest; read applies same XOR).
// WAR safety: stage(t+1) overwrites buf[cur^1], last read in iter t-1 whose
// readers retired before iter t-1's lgkmcnt(0)+barrier.
// ---------------------------------------------------------------------------
template <int MODE, int BM>
__global__ __launch_bounds__(256) void gemm_kernel(
    const bf16* __restrict__ A, const bf16* __restrict__ WT,
    const float* __restrict__ b0, const float* __restrict__ b1, const float* __restrict__ b2,
    int s1, int s2,
    void* __restrict__ o0, void* __restrict__ o1,
    int N, int K, int Kpart)
{
    constexpr int MT = BM / 32;
    __shared__ __align__(16) bf16 sA[2][BM * 32];
    __shared__ __align__(16) bf16 sB[2][128 * 32];

    const int tid  = threadIdx.x;
    const int lane = tid & 63;
    const int wave = tid >> 6;
    const int quad = lane >> 4;
    const int l15  = lane & 15;
    const int wm   = (wave >> 1) * (BM / 2);
    const int wn   = (wave & 1) * 64;

    int bxs, bys, bzs;
    xcd_swizzle(bxs, bys, bzs);
    const int bm = bys * BM;
    const int bn = bxs * 128;
    const int kbase = bzs * Kpart;

    f32x4 acc[MT][4];
#pragma unroll
    for (int i = 0; i < MT; i++)
#pragma unroll
        for (int j = 0; j < 4; j++)
#pragma unroll
            for (int r = 0; r < 4; r++) acc[i][j][r] = 0.0f;

    const int idx1 = tid + 256;
    // chunk (16B) staging indices; source col pre-swizzled by row (T2):
    const int ra0 = tid >> 2,  ca0 = (((tid  & 3) ^ ((ra0 >> 1) & 3)) * 8);
    const int rb1 = idx1 >> 2, cb1 = (((idx1 & 3) ^ ((rb1 >> 1) & 3)) * 8);

    const bf16* Arow0 = A + (size_t)(bm + ra0) * K + kbase + ca0;
    const bf16* Arow1 = (BM == 128) ? A + (size_t)(bm + rb1) * K + kbase + cb1 : A;
    const bf16* Brow0 = WT + (size_t)(bn + ra0) * K + kbase + ca0;
    const bf16* Brow1 = WT + (size_t)(bn + rb1) * K + kbase + cb1;

    const int nk = Kpart >> 5;

    // prologue: stage tile 0 into buffer 0
    async16(Arow0, sA[0] + tid * 8);
    if (BM == 128) async16(Arow1, sA[0] + idx1 * 8);
    async16(Brow0, sB[0] + tid * 8);
    async16(Brow1, sB[0] + idx1 * 8);

    // swizzled fragment column: for all frag rows R, (R>>1)&3 == (l15>>1)&3
    const int chF = (quad ^ ((l15 >> 1) & 3)) * 8;

    int cur = 0;
    for (int kt = 0; kt < nk; kt++) {
        if (kt + 1 < nk) {
            const int ko = (kt + 1) * 32;
            async16(Arow0 + ko, sA[cur ^ 1] + tid * 8);
            if (BM == 128) async16(Arow1 + ko, sA[cur ^ 1] + idx1 * 8);
            async16(Brow0 + ko, sB[cur ^ 1] + tid * 8);
            async16(Brow1 + ko, sB[cur ^ 1] + idx1 * 8);
            if (BM == 128) SYNC_VM(4);   // tile kt landed; kt+1 stays in flight
            else           SYNC_VM(3);
        } else {
            SYNC_VM(0);
        }
        bf16x8 af[MT], bfr[4];
#pragma unroll
        for (int i = 0; i < MT; i++)
            af[i] = *(const bf16x8*)(sA[cur] + (wm + i * 16 + l15) * 32 + chF);
#pragma unroll
        for (int i = 0; i < 4; i++)
            bfr[i] = *(const bf16x8*)(sB[cur] + (wn + i * 16 + l15) * 32 + chF);
#pragma unroll
        for (int mt = 0; mt < MT; mt++)
#pragma unroll
            for (int nt = 0; nt < 4; nt++)
                acc[mt][nt] = MFMA16(af[mt], bfr[nt], acc[mt][nt]);
        SYNC_LGKM();   // frag reads retired -> next overwrite of buf[cur] safe
        cur ^= 1;
    }

    void* outp = (bzs == 0) ? o0 : o1;

#pragma unroll
    for (int nt = 0; nt < 4; nt++) {
        const int col = bn + wn + nt * 16 + l15;
        float bias = 0.0f;
        if (MODE != 1)
            bias = (col < s1) ? b0[col] : (col < s2) ? b1[col - s1] : b2[col - s2];
#pragma unroll
        for (int mt = 0; mt < MT; mt++) {
#pragma unroll
            for (int r = 0; r < 4; r++) {
                const int row = bm + wm + mt * 16 + quad * 4 + r;
                float v = acc[mt][nt][r] + bias;
                if (MODE == 2) v = 0.5f * v * (1.0f + erff(v * 0.70710678118654752f));
                if (MODE == 1) ((float*)outp)[(size_t)row * N + col] = v;
                else           ((bf16*)outp)[(size_t)row * N + col] = (bf16)v;
            }
        }
    }
}

// ---------------------------------------------------------------------------
// V-transpose: qkv V-part [key][dim] -> vT[bh][dim][key].
// ---------------------------------------------------------------------------
__global__ __launch_bounds__(256) void vtrans_kernel(
    const bf16* __restrict__ qkv, bf16* __restrict__ vT)
{
    const int bh = blockIdx.y;
    const int b = bh / 12, h = bh - b * 12;
    const int k0 = blockIdx.x * 128;
    __shared__ __align__(16) bf16 tile[128 * 72];
    const int tid = threadIdx.x;
    const bf16* src = qkv + (size_t)(b * 512 + k0) * 2304 + 1536 + h * 64;
#pragma unroll
    for (int i = 0; i < 4; i++) {
        const int idx = i * 256 + tid;
        const int r = idx >> 3, c = (idx & 7) * 8;
        *(uint4*)(tile + r * 72 + c) = *(const uint4*)(src + (size_t)r * 2304 + c);
    }
    __syncthreads();
    bf16* dst = vT + (size_t)bh * 64 * 512 + k0;
#pragma unroll
    for (int i = 0; i < 4; i++) {
        const int idx = i * 256 + tid;
        const int d = idx & 63, kg = idx >> 6;
        alignas(16) bf16 tmp[8];
#pragma unroll
        for (int e = 0; e < 8; e++) tmp[e] = tile[(kg * 8 + e) * 72 + d];
        *(uint4*)(dst + (size_t)d * 512 + kg * 8) = *(uint4*)tmp;
    }
}

// ---------------------------------------------------------------------------
// Attention: one block = (b, h, 32-row Q tile), 256 threads = 4 waves.
// K/V staged via global_load_lds, double-buffered, counted vmcnt (T3/T4);
// tiles chunk-XOR swizzled: LDS[r][chunk j] = G[r][chunk j ^ (r&7)];
// Q fragments held in registers (loop-invariant, loaded from global once);
// V-stage(0) issued before softmax so its latency hides under softmax.
// ---------------------------------------------------------------------------
__global__ __launch_bounds__(256) void attn_kernel(
    const bf16* __restrict__ qkv, const bf16* __restrict__ vT,
    const float* __restrict__ mask, bf16* __restrict__ ctx)
{
    int bxs, bys, bzs;
    xcd_swizzle(bxs, bys, bzs);
    const int b = bzs, h = bys, q0 = bxs * 32;
    const int bh = b * 12 + h;
    const int tid = threadIdx.x, lane = tid & 63, wave = tid >> 6;
    const int quad = lane >> 4, l15 = lane & 15;
    const int mt = wave & 1;             // row half (0..1)
    const int whi = wave >> 1;           // col half (0..1)

    __shared__ __align__(16) bf16 sKV[2][64 * 64];
    __shared__ __align__(16) bf16 sS[32 * 520];
    __shared__ float sAM[512];
    __shared__ float sRed[256];          // shared max-then-sum buffer
    __shared__ float sRow[32];

    for (int i = tid; i < 512; i += 256)
        sAM[i] = (1.0f - mask[b * 512 + i]) * -10000.0f;

    const size_t RS = 2304;
    // Q fragments directly from global (loop-invariant)
    const bf16* Qrow = qkv + (size_t)(b * 512 + q0 + mt * 16 + l15) * RS + h * 64;
    const bf16x8 aQ0 = *(const bf16x8*)(Qrow + quad * 8);
    const bf16x8 aQ1 = *(const bf16x8*)(Qrow + 32 + quad * 8);

    // staging: 512 16B-chunks per 64x64 tile; 2 chunks/thread; src pre-swizzled
    const int c0 = tid, c1 = tid + 256;
    const int r0 = c0 >> 3, r1 = c1 >> 3;
    const int sc0 = ((c0 & 7) ^ (r0 & 7)) * 8;
    const int sc1 = ((c1 & 7) ^ (r1 & 7)) * 8;

    const bf16* Kbase = qkv + (size_t)(b * 512) * RS + 768 + h * 64;

    // stage K(0)
    async16(Kbase + (size_t)(r0) * RS + sc0, (bf16*)sKV[0] + c0 * 8);
    async16(Kbase + (size_t)(r1) * RS + sc1, (bf16*)sKV[0] + c1 * 8);

    // ---- phase B: S = Q @ K^T ----
#pragma unroll
    for (int kt = 0; kt < 8; kt++) {
        const int cur = kt & 1;
        if (kt < 7) {
            async16(Kbase + (size_t)((kt + 1) * 64 + r0) * RS + sc0, (bf16*)sKV[cur ^ 1] + c0 * 8);
            async16(Kbase + (size_t)((kt + 1) * 64 + r1) * RS + sc1, (bf16*)sKV[cur ^ 1] + c1 * 8);
            SYNC_VM(2);
        } else {
            SYNC_VM(0);
        }
#pragma unroll
        for (int n = 0; n < 2; n++) {
            const int nt = whi * 2 + n;
            const int krow = nt * 16 + l15;
            const int sw = krow & 7;
            bf16x8 bK0 = *(const bf16x8*)(sKV[cur] + krow * 64 + ((quad ^ sw) * 8));
            bf16x8 bK1 = *(const bf16x8*)(sKV[cur] + krow * 64 + (((4 + quad) ^ sw) * 8));
            f32x4 accS;
#pragma unroll
            for (int r = 0; r < 4; r++) accS[r] = 0.0f;
            accS = MFMA16(aQ0, bK0, accS);
            accS = MFMA16(aQ1, bK1, accS);
#pragma unroll
            for (int r = 0; r < 4; r++) {
                const int row = mt * 16 + quad * 4 + r;
                sS[row * 520 + kt * 64 + nt * 16 + l15] = (bf16)accS[r];
            }
        }
        SYNC_LGKM();
    }

    // stage V(0) now: latency hides under softmax (softmax syncs are lgkm-only)
    const bf16* Vbase = vT + (size_t)bh * 64 * 512;
    async16(Vbase + (size_t)r0 * 512 + sc0, (bf16*)sKV[0] + c0 * 8);
    async16(Vbase + (size_t)r1 * 512 + sc1, (bf16*)sKV[0] + c1 * 8);

    // ---- phase C: softmax (rows exclusive per 8-thread group) ----
    {
        const int r = tid >> 3, p = tid & 7;
        float mx = -1e30f;
#pragma unroll
        for (int t = 0; t < 8; t++) {
            const int v0 = (p + 8 * t) * 8;
            bf16x8 pv = *(const bf16x8*)(sS + r * 520 + v0);
#pragma unroll
            for (int e = 0; e < 8; e++)
                mx = fmaxf(mx, (float)pv[e] * 0.125f + sAM[v0 + e]);
        }
        sRed[r * 8 + p] = mx;
        SYNC_LGKM();
#pragma unroll
        for (int q = 0; q < 8; q++) mx = fmaxf(mx, sRed[r * 8 + q]);
        float sum = 0.0f;
#pragma unroll
        for (int t = 0; t < 8; t++) {
            const int v0 = (p + 8 * t) * 8;
            bf16x8 pv = *(const bf16x8*)(sS + r * 520 + v0);
            bf16x8 ev;
#pragma unroll
            for (int e = 0; e < 8; e++) {
                const float x = __expf((float)pv[e] * 0.125f + sAM[v0 + e] - mx);
                sum += x;
                ev[e] = (bf16)x;
            }
            *(bf16x8*)(sS + r * 520 + v0) = ev;
        }
        SYNC_LGKM();               // all max-reads done before sRed reuse
        sRed[r * 8 + p] = sum;
        SYNC_LGKM();
        if (p == 0) {
            float s = 0.0f;
#pragma unroll
            for (int q = 0; q < 8; q++) s += sRed[r * 8 + q];
            sRow[r] = s;
        }
    }

    // ---- phase D: O = P @ V (V from vT, [dim][key] tiles) ----
    f32x4 accO[2];
#pragma unroll
    for (int i = 0; i < 2; i++)
#pragma unroll
        for (int r = 0; r < 4; r++) accO[i][r] = 0.0f;

#pragma unroll
    for (int kt = 0; kt < 8; kt++) {
        const int cur = kt & 1;
        if (kt < 7) {
            async16(Vbase + (size_t)r0 * 512 + (kt + 1) * 64 + sc0, (bf16*)sKV[cur ^ 1] + c0 * 8);
            async16(Vbase + (size_t)r1 * 512 + (kt + 1) * 64 + sc1, (bf16*)sKV[cur ^ 1] + c1 * 8);
            SYNC_VM(2);
        } else {
            SYNC_VM(0);
        }
#pragma unroll
        for (int kk = 0; kk < 2; kk++) {
            bf16x8 aP = *(const bf16x8*)(sS + (mt * 16 + l15) * 520 + kt * 64 + kk * 32 + quad * 8);
#pragma unroll
            for (int n = 0; n < 2; n++) {
                const int vrow = whi * 32 + n * 16 + l15;
                bf16x8 bV = *(const bf16x8*)(sKV[cur] + vrow * 64 + (((kk * 4 + quad) ^ (vrow & 7)) * 8));
                accO[n] = MFMA16(aP, bV, accO[n]);
            }
        }
        SYNC_LGKM();
    }
#pragma unroll
    for (int n = 0; n < 2; n++) {
#pragma unroll
        for (int r = 0; r < 4; r++) {
            const int row = mt * 16 + quad * 4 + r;
            const float o = accO[n][r] / sRow[row];
            ctx[(size_t)(b * 512 + q0 + row) * 768 + h * 64 + whi * 32 + n * 16 + l15] = (bf16)o;
        }
    }
}

// ---------------------------------------------------------------------------
// Fused split-K reduce + bias + residual-add + LayerNorm.
// ---------------------------------------------------------------------------
template <int NP>
__global__ __launch_bounds__(256) void ln_kernel(
    const float* __restrict__ p0, const float* __restrict__ p1,
    const float* __restrict__ bias, const float* __restrict__ resid,
    const float* __restrict__ g, const float* __restrict__ bb,
    bf16* __restrict__ out_bf, float* __restrict__ out_f32)
{
    const int row = blockIdx.x;
    const int tid = threadIdx.x;
    __shared__ float sS[4], sQ[4];

    float x[3], s = 0.0f, sq = 0.0f;
#pragma unroll
    for (int j = 0; j < 3; j++) {
        const int c = tid + j * 256;
        const size_t idx = (size_t)row * 768 + c;
        float v = p0[idx] + bias[c] + resid[idx];
        if (NP > 1) v += p1[idx];
        x[j] = v; s += v; sq += v * v;
    }
#pragma unroll
    for (int off = 32; off; off >>= 1) { s += __shfl_down(s, off); sq += __shfl_down(sq, off); }
    if ((tid & 63) == 0) { sS[tid >> 6] = s; sQ[tid >> 6] = sq; }
    __syncthreads();
    s  = sS[0] + sS[1] + sS[2] + sS[3];
    sq = sQ[0] + sQ[1] + sQ[2] + sQ[3];
    const float mean = s * (1.0f / 768.0f);
    float var = sq * (1.0f / 768.0f) - mean * mean;
    var = fmaxf(var, 0.0f);
    const float rstd = rsqrtf(var + 1e-12f);
#pragma unroll
    for (int j = 0; j < 3; j++) {
        const int c = tid + j * 256;
        const float v = (x[j] - mean) * rstd * g[c] + bb[c];
        out_bf[(size_t)row * 768 + c] = (bf16)v;
        out_f32[(size_t)row * 768 + c] = v;
    }
}

// ---------------------------------------------------------------------------
// Transpose + quantize all 6 fp32 weight matrices of one layer into bf16 wT.
// ---------------------------------------------------------------------------
__global__ __launch_bounds__(256) void transpose_kernel(
    const float* __restrict__ Wq, const float* __restrict__ Wk, const float* __restrict__ Wv,
    const float* __restrict__ Wao, const float* __restrict__ Wi, const float* __restrict__ Wo,
    bf16* __restrict__ wT)
{
    __shared__ bf16 tile[64 * 68];
    int id = blockIdx.x;
    const float* src; bf16* dst; int Kd, Nd;
    if (id < 576) {
        const int w = id / 144; id -= w * 144;
        Kd = 768; Nd = 768;
        src = (w == 0) ? Wq : (w == 1) ? Wk : (w == 2) ? Wv : Wao;
        dst = wT + (size_t)w * 589824;
    } else if (id < 1152) {
        id -= 576; Kd = 768; Nd = 3072; src = Wi; dst = wT + 2359296;
    } else {
        id -= 1152; Kd = 3072; Nd = 768; src = Wo; dst = wT + 4718592;
    }
    const int tn = Nd >> 6;
    const int tr = id / tn, tc = id - tr * tn;
    const int r0 = tr * 64, c0 = tc * 64;
    const int tid = threadIdx.x;

#pragma unroll
    for (int i = 0; i < 4; i++) {
        const int idx = i * 256 + tid;
        const int r = idx >> 4, c4 = (idx & 15) * 4;
        const float4 f = *(const float4*)(src + (size_t)(r0 + r) * Nd + c0 + c4);
        alignas(8) bf16 q[4] = {(bf16)f.x, (bf16)f.y, (bf16)f.z, (bf16)f.w};
        *(ushort4*)(tile + r * 68 + c4) = *(ushort4*)q;
    }
    __syncthreads();
#pragma unroll
    for (int i = 0; i < 4; i++) {
        const int idx = i * 256 + tid;
        const int n = idx >> 4, kc = (idx & 15) * 4;
        alignas(8) bf16 tmp[4];
#pragma unroll
        for (int e = 0; e < 4; e++) tmp[e] = tile[(kc + e) * 68 + n];
        *(ushort4*)(dst + (size_t)(c0 + n) * Kd + r0 + kc) = *(ushort4*)tmp;
    }
}

__global__ __launch_bounds__(256) void convert_kernel(
    const float* __restrict__ in, bf16* __restrict__ out, int n)
{
    const int i = blockIdx.x * 256 + threadIdx.x;
    if (i < n) out[i] = (bf16)in[i];
}

// ---------------------------------------------------------------------------
extern "C" void kernel_launch(void* const* d_in, const int* in_sizes, int n_in,
                              void* d_out, int out_size, void* d_ws, size_t ws_size,
                              hipStream_t stream)
{
    const float* hidden = (const float*)d_in[0];
    const float* mask   = (const float*)d_in[1];
    const float* Wq  = (const float*)d_in[2];  const float* bq  = (const float*)d_in[3];
    const float* Wk  = (const float*)d_in[4];  const float* bk  = (const float*)d_in[5];
    const float* Wv  = (const float*)d_in[6];  const float* bv  = (const float*)d_in[7];
    const float* Wao = (const float*)d_in[8];  const float* bao = (const float*)d_in[9];
    const float* g1  = (const float*)d_in[10]; const float* be1 = (const float*)d_in[11];
    const float* Wi  = (const float*)d_in[12]; const float* bi  = (const float*)d_in[13];
    const float* Wo  = (const float*)d_in[14]; const float* bo  = (const float*)d_in[15];
    const float* g2  = (const float*)d_in[16]; const float* be2 = (const float*)d_in[17];

    // workspace layout (95,944,704 B) — identical to r2 (lifetime-checked):
    char* ws = (char*)d_ws;
    bf16*  wT    = (bf16*)(ws);
    bf16*  qkv   = (bf16*)(ws + 14155776);
    bf16*  vT    = (bf16*)(ws + 33030144);
    bf16*  ctx   = (bf16*)(ws + 39321600);
    bf16*  attnb = (bf16*)(ws + 45613056);
    bf16*  xb    = (bf16*)(ws + 51904512);
    float* xf    = (float*)(ws + 58195968);
    float* attnf = (float*)(ws + 70778880);
    bf16*  ffh   = (bf16*)(ws + 14155776);
    float* pA0   = (float*)(ws + 14155776);
    float* pF0   = (float*)(ws + 39321600);
    float* pF1   = (float*)(ws + 83361792);

    convert_kernel<<<12288, 256, 0, stream>>>(hidden, xb, 3145728);

    for (int l = 0; l < 12; l++) {
        transpose_kernel<<<1728, 256, 0, stream>>>(
            Wq + (size_t)l * 589824, Wk + (size_t)l * 589824, Wv + (size_t)l * 589824,
            Wao + (size_t)l * 589824, Wi + (size_t)l * 2359296, Wo + (size_t)l * 2359296, wT);

        // QKV: M=4096 N=2304 K=768, BM=64 -> 1152 blocks
        gemm_kernel<0, 64><<<dim3(18, 64, 1), 256, 0, stream>>>(
            xb, wT, bq + l * 768, bk + l * 768, bv + l * 768, 768, 1536,
            qkv, nullptr, 2304, 768, 768);

        vtrans_kernel<<<dim3(4, 96), 256, 0, stream>>>(qkv, vT);

        attn_kernel<<<dim3(16, 12, 8), 256, 0, stream>>>(qkv, vT, mask, ctx);

        // AO: M=4096 N=768 K=768, BM=64 -> 384 blocks, f32 out
        gemm_kernel<1, 64><<<dim3(6, 64, 1), 256, 0, stream>>>(
            ctx, wT + 1769472, nullptr, nullptr, nullptr, 0, 0,
            pA0, nullptr, 768, 768, 768);

        const float* resid1 = (l == 0) ? hidden : xf;
        ln_kernel<1><<<4096, 256, 0, stream>>>(
            pA0, nullptr, bao + l * 768, resid1, g1 + l * 768, be1 + l * 768, attnb, attnf);

        // FF1: M=4096 N=3072 K=768, BM=128 -> 768 blocks
        gemm_kernel<2, 128><<<dim3(24, 32, 1), 256, 0, stream>>>(
            attnb, wT + 2359296, bi + l * 3072, bi + l * 3072, bi + l * 3072, 3072, 3072,
            ffh, nullptr, 3072, 768, 768);

        // FF2: M=4096 N=768 K=3072, BM=64 split-2 -> 768 blocks
        gemm_kernel<1, 64><<<dim3(6, 64, 2), 256, 0, stream>>>(
            ffh, wT + 4718592, nullptr, nullptr, nullptr, 0, 0,
            pF0, pF1, 768, 3072, 1536);

        float* f32dst = (l == 11) ? (float*)d_out : xf;
        ln_kernel<2><<<4096, 256, 0, stream>>>(
            pF0, pF1, bo + l * 768, attnf, g2 + l * 768, be2 + l * 768, xb, f32dst);
    }
}